// Round 8
// baseline (1417.966 us; speedup 1.0000x reference)
//
#include <hip/hip_runtime.h>

#define N_USERS 50000
#define N_ENT   150000
#define N_NODES 200000
#define NE      2000000
#define BATCH   8192
#define NB 782          // ceil(N_NODES / 256)
#define EBATCH 24       // edges staged per wave batch (P(deg>24) ~ 1e-5)

__device__ __forceinline__ float bf2f(unsigned short b) {
    return __uint_as_float(((unsigned int)b) << 16);
}
__device__ __forceinline__ unsigned short f2bf(float f) {
    unsigned int u = __float_as_uint(f);
    u += 0x7FFF + ((u >> 16) & 1);          // round-to-nearest-even
    return (unsigned short)(u >> 16);
}

// ===========================================================================
// CSR build: histogram -> exclusive scan -> atomic-cursor fill.
// After fill, rs[r] == row_end; row_start = rs[r] - deg[r].
// ===========================================================================
__global__ __launch_bounds__(256) void hist_kernel(const int* __restrict__ rows,
                                                   int* __restrict__ deg) {
    int e = blockIdx.x * 256 + threadIdx.x;
    if (e < NE) atomicAdd(&deg[rows[e]], 1);
}

__global__ __launch_bounds__(256) void scan1(const int* __restrict__ deg,
                                             int* __restrict__ rs,
                                             int* __restrict__ blk) {
    __shared__ int buf[256];
    int i = blockIdx.x * 256 + threadIdx.x;
    int v = (i < N_NODES) ? deg[i] : 0;
    buf[threadIdx.x] = v;
    __syncthreads();
    for (int off = 1; off < 256; off <<= 1) {
        int x = (threadIdx.x >= off) ? buf[threadIdx.x - off] : 0;
        __syncthreads();
        buf[threadIdx.x] += x;
        __syncthreads();
    }
    if (i < N_NODES) rs[i] = buf[threadIdx.x] - v;       // exclusive
    if (threadIdx.x == 255) blk[blockIdx.x] = buf[255];
}

__global__ __launch_bounds__(1024) void scan2(int* __restrict__ blk) {
    __shared__ int buf[1024];
    int t = threadIdx.x;
    int v = (t < NB) ? blk[t] : 0;
    buf[t] = v;
    __syncthreads();
    for (int off = 1; off < 1024; off <<= 1) {
        int x = (t >= off) ? buf[t - off] : 0;
        __syncthreads();
        buf[t] += x;
        __syncthreads();
    }
    if (t < NB) blk[t] = buf[t] - v;
}

__global__ __launch_bounds__(256) void scan3(int* __restrict__ rs,
                                             const int* __restrict__ blk) {
    int i = blockIdx.x * 256 + threadIdx.x;
    if (i < N_NODES) rs[i] += blk[blockIdx.x];
}

__global__ __launch_bounds__(256) void fill_kernel(const int* __restrict__ rows,
                                                   const int* __restrict__ cols,
                                                   const float* __restrict__ vals,
                                                   int* __restrict__ rs,
                                                   int* __restrict__ ccol,
                                                   float* __restrict__ cval) {
    int e = blockIdx.x * 256 + threadIdx.x;
    if (e >= NE) return;
    int pos = atomicAdd(&rs[rows[e]], 1);
    ccol[pos] = cols[e];
    cval[pos] = vals[e];
}

// ---------------------------------------------------------------------------
// t0 = bf16(concat(ue, ee)) — 64-dim row = 128 B = one cache line.
// ---------------------------------------------------------------------------
__global__ __launch_bounds__(256) void build_t0(const float* __restrict__ ue,
                                                const float* __restrict__ ee,
                                                unsigned short* __restrict__ t0) {
    int i = blockIdx.x * 256 + threadIdx.x;              // float4 index
    const int total = N_NODES * 64 / 4;
    if (i >= total) return;
    const int uelems = N_USERS * 64 / 4;
    float4 v = (i < uelems) ? ((const float4*)ue)[i]
                            : ((const float4*)ee)[i - uelems];
    ushort4 o;
    o.x = f2bf(v.x); o.y = f2bf(v.y); o.z = f2bf(v.z); o.w = f2bf(v.w);
    ((ushort4*)t0)[i] = o;
}

// ===========================================================================
// Fused per-layer kernel, round-8 gather: one wave per row; per edge batch
// (<=24 edges) issue ASYNC global_load_lds (32 lanes x 4B = the 128B bf16 row;
// LDS dest = wave-uniform base + lane*4 — m97-verified), one s_waitcnt
// vmcnt(0), then consume via ds_read_u16 (2-way bank alias = free).
// No data VGPRs -> up to 24 lines in flight per wave (~380/CU at 16 waves)
// vs 4 with register staging (r7's latency cap: 4.3 G lines/s measured).
// Block = 512 (8 waves) keeps LDS <= 56.5 KB -> 2 blocks/CU.
// ===========================================================================
template <int DIN, int DOUT, int L0, int WT>
__global__ __launch_bounds__(512) void spmm_transform(
        const int* __restrict__ rs, const int* __restrict__ deg,
        const int* __restrict__ ccol, const float* __restrict__ cval,
        const unsigned short* __restrict__ tin,
        const float* __restrict__ ue, const float* __restrict__ ee,
        const float* __restrict__ xin,            // fp32 prev layer (stride DIN)
        const float* __restrict__ Wg, const float* __restrict__ bg,
        const float* __restrict__ Wb, const float* __restrict__ bb,
        float* __restrict__ xout,                 // fp32, stride DOUT
        unsigned short* __restrict__ tout,        // bf16, stride DOUT (if WT)
        float* __restrict__ norm_out) {
    __shared__ float sWg[DIN * DOUT];
    __shared__ float sWb[DIN * DOUT];
    __shared__ float sbg[DOUT];
    __shared__ float sbb[DOUT];
    __shared__ unsigned short gbuf[8 * EBATCH * DIN];   // per-wave staging
    for (int i = threadIdx.x; i < DIN * DOUT; i += 512) {
        sWg[i] = Wg[i];
        sWb[i] = Wb[i];
    }
    if (threadIdx.x < DOUT) {
        sbg[threadIdx.x] = bg[threadIdx.x];
        sbb[threadIdx.x] = bb[threadIdx.x];
    }
    __syncthreads();

    const int lane = threadIdx.x & 63;
    const int wave = threadIdx.x >> 6;
    unsigned short* mybuf = &gbuf[wave * EBATCH * DIN];
    const int row  = (blockIdx.x * 512 + threadIdx.x) >> 6;   // grid exact

    float acc0 = 0.f, acc1 = 0.f;
    const int end   = rs[row];
    const int start = end - deg[row];
    for (int base = start; base < end; base += EBATCH) {
        int nb = end - base;                     // wave-uniform
        if (nb > EBATCH) nb = EBATCH;
        int   mycol = 0;
        float myval = 0.f;                       // pad lanes contribute 0
        if (lane < nb) {
            mycol = ccol[base + lane];
            myval = cval[base + lane];
        }
        // ---- issue async gathers (no data VGPRs, all in flight) ----
        if (lane < (DIN / 2)) {
            for (int u = 0; u < nb; u++) {
                unsigned int cu = (unsigned int)__builtin_amdgcn_readlane(mycol, u);
                const unsigned int* gp = (const unsigned int*)(tin + (size_t)cu * DIN);
                __builtin_amdgcn_global_load_lds(
                    (const __attribute__((address_space(1))) unsigned int*)(gp + lane),
                    (__attribute__((address_space(3))) unsigned int*)(mybuf + u * DIN),
                    4, 0, 0);
            }
        }
        if (DIN == 32 && (nb & 1) && lane < 32) {
            mybuf[nb * 32 + lane] = 0;           // zero pad slot (NaN guard)
        }
        asm volatile("s_waitcnt vmcnt(0)" ::: "memory");
        // ---- consume from LDS ----
        if (DIN == 64) {
            for (int u = 0; u < nb; u++) {
                float v = __uint_as_float(
                    __builtin_amdgcn_readlane(__float_as_uint(myval), u));
                float x = bf2f(mybuf[u * 64 + lane]);
                if (u & 1) acc1 = fmaf(v, x, acc1);
                else       acc0 = fmaf(v, x, acc0);
            }
        } else {  // DIN==32: lanes 0-31 = edge u, lanes 32-63 = edge u+1
            for (int u = 0; u < nb; u += 2) {
                float v0 = __uint_as_float(
                    __builtin_amdgcn_readlane(__float_as_uint(myval), u));
                float v1 = __uint_as_float(
                    __builtin_amdgcn_readlane(__float_as_uint(myval), u + 1));
                float v = (lane < 32) ? v0 : v1;
                float x = bf2f(mybuf[u * 32 + lane]);
                if (u & 2) acc1 = fmaf(v, x, acc1);
                else       acc0 = fmaf(v, x, acc0);
            }
        }
        asm volatile("" ::: "memory");   // fence consume-reads vs next issue
    }
    float acc = acc0 + acc1;
    if (DIN == 32) acc += __shfl_xor(acc, 32);   // combine the 2 edge sub-slots

    // ---- own ego value (fp32) ----
    float e = 0.f;
    if (lane < DIN) {
        if (L0) {
            e = (row < N_USERS) ? ue[(size_t)row * 64 + lane]
                                : ee[(size_t)(row - N_USERS) * 64 + lane];
        } else {
            e = xin[(size_t)row * DIN + lane];
        }
    }
    float h = e + acc;
    float p = e * acc;

    // ---- dense transform via wave broadcast ----
    float ag = (lane < DOUT) ? sbg[lane] : 0.f;
    float ab = (lane < DOUT) ? sbb[lane] : 0.f;
#pragma unroll
    for (int k = 0; k < DIN; k++) {
        float hk = __shfl(h, k);
        float pk = __shfl(p, k);
        if (lane < DOUT) {
            ag = fmaf(hk, sWg[k * DOUT + lane], ag);
            ab = fmaf(pk, sWb[k * DOUT + lane], ab);
        }
    }
    ag = ag > 0.f ? ag : 0.01f * ag;   // leaky_relu slope 0.01
    ab = ab > 0.f ? ab : 0.01f * ab;
    float nv = (lane < DOUT) ? (ag + ab) : 0.f;

    float ss = nv * nv;
#pragma unroll
    for (int off = 32; off > 0; off >>= 1) ss += __shfl_xor(ss, off);
    float nrm = fmaxf(sqrtf(ss), 1e-12f);

    if (lane < DOUT) {
        xout[(size_t)row * DOUT + lane] = nv;
        if (WT) tout[(size_t)row * DOUT + lane] = f2bf(nv);
    }
    if (lane == 0) norm_out[row] = nrm;
}

// ===========================================================================
// Scoring: one wave per batch element; sections 64 raw + 64/n0 + 32/n1 + 16/n2
// (normalization folded in as division by the norm product — r5-verified).
// ===========================================================================
__global__ __launch_bounds__(256) void score_kernel(
        const int* __restrict__ users, const int* __restrict__ pos,
        const int* __restrict__ neg,
        const float* __restrict__ ue, const float* __restrict__ ee,
        const float* __restrict__ e1, const float* __restrict__ n0,
        const float* __restrict__ e2, const float* __restrict__ n1,
        const float* __restrict__ e3, const float* __restrict__ n2,
        float* __restrict__ out) {
    int gid  = blockIdx.x * 256 + threadIdx.x;
    int idx  = gid >> 6;
    int lane = gid & 63;
    if (idx >= BATCH) return;
    int u  = users[idx];
    int pe = pos[idx];
    int ne = neg[idx];
    int pn = N_USERS + pe;
    int nn = N_USERS + ne;

    float s1p = 1.0f / (n0[u] * n0[pn]);
    float s1n = 1.0f / (n0[u] * n0[nn]);
    float s2p = 1.0f / (n1[u] * n1[pn]);
    float s2n = 1.0f / (n1[u] * n1[nn]);
    float s3p = 1.0f / (n2[u] * n2[pn]);
    float s3n = 1.0f / (n2[u] * n2[nn]);

    float ap = 0.f, an = 0.f;
    {
        float xu = ue[(size_t)u * 64 + lane];
        ap += xu * ee[(size_t)pe * 64 + lane];
        an += xu * ee[(size_t)ne * 64 + lane];
    }
    {
        float xu = e1[(size_t)u * 64 + lane];
        ap += xu * e1[(size_t)pn * 64 + lane] * s1p;
        an += xu * e1[(size_t)nn * 64 + lane] * s1n;
    }
    if (lane < 32) {
        float xu = e2[(size_t)u * 32 + lane];
        ap += xu * e2[(size_t)pn * 32 + lane] * s2p;
        an += xu * e2[(size_t)nn * 32 + lane] * s2n;
    } else if (lane < 48) {
        int d = lane - 32;
        float xu = e3[(size_t)u * 16 + d];
        ap += xu * e3[(size_t)pn * 16 + d] * s3p;
        an += xu * e3[(size_t)nn * 16 + d] * s3n;
    }
#pragma unroll
    for (int off = 32; off > 0; off >>= 1) {
        ap += __shfl_xor(ap, off);
        an += __shfl_xor(an, off);
    }
    if (lane == 0) {
        out[2 * idx + 0] = ap;
        out[2 * idx + 1] = an;
    }
}

// ===========================================================================
extern "C" void kernel_launch(void* const* d_in, const int* in_sizes, int n_in,
                              void* d_out, int out_size, void* d_ws, size_t ws_size,
                              hipStream_t stream) {
    const int*   users = (const int*)d_in[0];
    const int*   pos   = (const int*)d_in[1];
    const int*   neg   = (const int*)d_in[2];
    const int*   rows  = (const int*)d_in[3];
    const int*   cols  = (const int*)d_in[4];
    const float* vals  = (const float*)d_in[5];
    const float* ue    = (const float*)d_in[6];
    const float* ee    = (const float*)d_in[7];
    const float* Wg0 = (const float*)d_in[8],  *bg0 = (const float*)d_in[9];
    const float* Wb0 = (const float*)d_in[10], *bb0 = (const float*)d_in[11];
    const float* Wg1 = (const float*)d_in[12], *bg1 = (const float*)d_in[13];
    const float* Wb1 = (const float*)d_in[14], *bb1 = (const float*)d_in[15];
    const float* Wg2 = (const float*)d_in[16], *bg2 = (const float*)d_in[17];
    const float* Wb2 = (const float*)d_in[18], *bb2 = (const float*)d_in[19];

    // workspace (~174 MB; >=192 MB proven available in round 2)
    float* e1 = (float*)d_ws;                            // N x 64 fp32 (unnorm)
    float* e2 = e1 + (size_t)N_NODES * 64;               // N x 32
    float* e3 = e2 + (size_t)N_NODES * 32;               // N x 16
    float* n0 = e3 + (size_t)N_NODES * 16;               // N
    float* n1 = n0 + N_NODES;                            // N
    float* n2 = n1 + N_NODES;                            // N
    float* cval = n2 + N_NODES;                          // E
    unsigned short* t0 = (unsigned short*)(cval + NE);   // N x 64 bf16
    unsigned short* t1 = t0 + (size_t)N_NODES * 64;      // N x 64 bf16
    unsigned short* t2 = t1 + (size_t)N_NODES * 64;      // N x 32 bf16
    int* ccol = (int*)(t2 + (size_t)N_NODES * 32);       // E
    int* deg  = ccol + NE;                               // N
    int* rs   = deg + N_NODES;                           // N
    int* blk  = rs + N_NODES;                            // 1024

    // ---- CSR build + bf16 layer-0 table (once) ----
    hipMemsetAsync(deg, 0, N_NODES * sizeof(int), stream);
    hist_kernel<<<(NE + 255) / 256, 256, 0, stream>>>(rows, deg);
    scan1<<<NB, 256, 0, stream>>>(deg, rs, blk);
    scan2<<<1, 1024, 0, stream>>>(blk);
    scan3<<<NB, 256, 0, stream>>>(rs, blk);
    fill_kernel<<<(NE + 255) / 256, 256, 0, stream>>>(rows, cols, vals, rs, ccol, cval);
    build_t0<<<(N_NODES * 64 / 4 + 255) / 256, 256, 0, stream>>>(ue, ee, t0);

    // ---- 3 fused layers: wave per row, block=512, async LDS-staged gather ----
    const int grid = N_NODES * 64 / 512;  // 25000, exact
    spmm_transform<64, 64, 1, 1><<<grid, 512, 0, stream>>>(
        rs, deg, ccol, cval, t0, ue, ee, nullptr,
        Wg0, bg0, Wb0, bb0, e1, t1, n0);
    spmm_transform<64, 32, 0, 1><<<grid, 512, 0, stream>>>(
        rs, deg, ccol, cval, t1, ue, ee, e1,
        Wg1, bg1, Wb1, bb1, e2, t2, n1);
    spmm_transform<32, 16, 0, 0><<<grid, 512, 0, stream>>>(
        rs, deg, ccol, cval, t2, ue, ee, e2,
        Wg2, bg2, Wb2, bb2, e3, nullptr, n2);

    // ---- scoring ----
    score_kernel<<<(BATCH * 64) / 256, 256, 0, stream>>>(users, pos, neg, ue, ee,
                                                         e1, n0, e2, n1, e3, n2,
                                                         (float*)d_out);
}